// Round 1
// baseline (940.829 us; speedup 1.0000x reference)
//
#include <hip/hip_runtime.h>

// Problem constants (validated against in_sizes at launch)
#define DD    64
#define WCOLS 68   // D + EF

__device__ __forceinline__ float lane_bcast(float v, int k) {
    return __int_as_float(__builtin_amdgcn_readlane(__float_as_int(v), k));
}

// ---------------------------------------------------------------------------
// init: x0 = emb[x_ids];  Y = x0 @ W1a.T + b1;  agg = 0
// wave-per-node-group (4 nodes), W1a.T staged in LDS column-major (conflict-free)
// ---------------------------------------------------------------------------
__global__ __launch_bounds__(256) void init_kernel(
    const int* __restrict__ x_ids, const float* __restrict__ emb,
    const float* __restrict__ W1, const float* __restrict__ b1,
    float* __restrict__ x0, float* __restrict__ Y, float* __restrict__ agg, int N)
{
    __shared__ float WaT[64 * 64];              // WaT[k*64+d] = W1[d][k]
    for (int i = threadIdx.x; i < 64 * 64; i += 256) {
        int d = i & 63, k = i >> 6;
        WaT[i] = W1[d * WCOLS + k];
    }
    __syncthreads();

    int lane = threadIdx.x & 63;
    int wid  = (blockIdx.x * 256 + threadIdx.x) >> 6;
    int nw   = (gridDim.x * 256) >> 6;
    float bias = b1[lane];

    for (int base = wid * 4; base < N; base += nw * 4) {
        int nvalid = N - base; if (nvalid > 4) nvalid = 4;
        float xv[4], acc[4];
        #pragma unroll
        for (int j = 0; j < 4; ++j) {
            xv[j] = (j < nvalid) ? emb[x_ids[base + j] * DD + lane] : 0.f;
            acc[j] = bias;
        }
        #pragma unroll 8
        for (int k = 0; k < 64; ++k) {
            float w = WaT[k * 64 + lane];
            #pragma unroll
            for (int j = 0; j < 4; ++j)
                acc[j] = fmaf(w, lane_bcast(xv[j], k), acc[j]);
        }
        #pragma unroll
        for (int j = 0; j < 4; ++j) {
            if (j < nvalid) {
                size_t o = (size_t)(base + j) * DD + lane;
                x0[o]  = xv[j];
                Y[o]   = acc[j];
                agg[o] = 0.f;
            }
        }
    }
}

// ---------------------------------------------------------------------------
// edge: agg[dst] += relu(Y[src] + We·e)   (relu-skip predicated atomics)
// wave-per-edge, 2-edge unroll for MLP/latency overlap
// ---------------------------------------------------------------------------
__global__ __launch_bounds__(256) void edge_kernel(
    const float* __restrict__ Y, const float* __restrict__ eattr,
    const int* __restrict__ src, const int* __restrict__ dst,
    const float* __restrict__ Wm, float* __restrict__ agg, int E)
{
    int lane = threadIdx.x & 63;
    int wid  = __builtin_amdgcn_readfirstlane((blockIdx.x * 256 + (int)threadIdx.x) >> 6);
    int nw   = (gridDim.x * 256) >> 6;

    float w0 = Wm[lane * WCOLS + 64];
    float w1 = Wm[lane * WCOLS + 65];
    float w2 = Wm[lane * WCOLS + 66];
    float w3 = Wm[lane * WCOLS + 67];

    for (int e = wid * 2; e < E; e += nw * 2) {
        int s0 = src[e], d0 = dst[e];
        float4 ea0 = *(const float4*)(eattr + (size_t)e * 4);
        float y0 = Y[(size_t)s0 * DD + lane];
        float m0 = y0 + w0 * ea0.x + w1 * ea0.y + w2 * ea0.z + w3 * ea0.w;

        int e1 = e + 1;
        if (e1 < E) {
            int s1 = src[e1], d1 = dst[e1];
            float4 ea1 = *(const float4*)(eattr + (size_t)e1 * 4);
            float y1 = Y[(size_t)s1 * DD + lane];
            float m1 = y1 + w0 * ea1.x + w1 * ea1.y + w2 * ea1.z + w3 * ea1.w;
            if (m0 > 0.f) unsafeAtomicAdd(&agg[(size_t)d0 * DD + lane], m0);
            if (m1 > 0.f) unsafeAtomicAdd(&agg[(size_t)d1 * DD + lane], m1);
        } else {
            if (m0 > 0.f) unsafeAtomicAdd(&agg[(size_t)d0 * DD + lane], m0);
        }
    }
}

// ---------------------------------------------------------------------------
// node update: o = relu((x+agg)@Wu.T + bu)
//   FUSE_Y: also Y = o@WnA.T + bn (next round), re-zero agg, store x_out=o
//   FINAL:  only accumulate mean(o) into out_mean (no x_out store)
// ---------------------------------------------------------------------------
template<bool FUSE_Y, bool FINAL>
__global__ __launch_bounds__(256) void node_kernel(
    const float* __restrict__ x_in, const float* __restrict__ agg,
    const float* __restrict__ Wu, const float* __restrict__ bu,
    const float* __restrict__ Wn, const float* __restrict__ bn,
    float* __restrict__ x_out, float* __restrict__ Y_out, float* __restrict__ aggz,
    float* __restrict__ out_mean, int N, float inv_n)
{
    __shared__ float WuT[64 * 64];
    __shared__ float WnT[FUSE_Y ? 64 * 64 : 1];
    __shared__ float red[FINAL ? 256 : 1];
    for (int i = threadIdx.x; i < 64 * 64; i += 256) {
        int d = i & 63, k = i >> 6;
        WuT[i] = Wu[d * DD + k];
        if (FUSE_Y) WnT[i] = Wn[d * WCOLS + k];
    }
    __syncthreads();

    int lane = threadIdx.x & 63;
    int wid  = (blockIdx.x * 256 + threadIdx.x) >> 6;
    int nw   = (gridDim.x * 256) >> 6;
    float biasu = bu[lane];
    float biasn = FUSE_Y ? bn[lane] : 0.f;
    float lsum = 0.f;

    for (int base = wid * 4; base < N; base += nw * 4) {
        int nvalid = N - base; if (nvalid > 4) nvalid = 4;
        float v[4], acc[4];
        #pragma unroll
        for (int j = 0; j < 4; ++j) {
            size_t o = (size_t)(base + j) * DD + lane;
            v[j]  = (j < nvalid) ? (x_in[o] + agg[o]) : 0.f;
            acc[j] = biasu;
        }
        #pragma unroll 8
        for (int k = 0; k < 64; ++k) {
            float w = WuT[k * 64 + lane];
            #pragma unroll
            for (int j = 0; j < 4; ++j)
                acc[j] = fmaf(w, lane_bcast(v[j], k), acc[j]);
        }
        float o4[4];
        #pragma unroll
        for (int j = 0; j < 4; ++j) o4[j] = fmaxf(acc[j], 0.f);

        if (FUSE_Y) {
            float acc2[4];
            #pragma unroll
            for (int j = 0; j < 4; ++j) acc2[j] = biasn;
            #pragma unroll 8
            for (int k = 0; k < 64; ++k) {
                float w = WnT[k * 64 + lane];
                #pragma unroll
                for (int j = 0; j < 4; ++j)
                    acc2[j] = fmaf(w, lane_bcast(o4[j], k), acc2[j]);
            }
            #pragma unroll
            for (int j = 0; j < 4; ++j) {
                if (j < nvalid) {
                    size_t o = (size_t)(base + j) * DD + lane;
                    x_out[o] = o4[j];
                    Y_out[o] = acc2[j];
                    aggz[o]  = 0.f;
                }
            }
        }
        if (FINAL) {
            #pragma unroll
            for (int j = 0; j < 4; ++j)
                if (j < nvalid) lsum += o4[j];
        }
    }

    if (FINAL) {
        red[threadIdx.x] = lsum;
        __syncthreads();
        if (threadIdx.x < 64) {
            float s = red[threadIdx.x] + red[threadIdx.x + 64] +
                      red[threadIdx.x + 128] + red[threadIdx.x + 192];
            unsafeAtomicAdd(&out_mean[threadIdx.x], s * inv_n);
        }
    }
}

// ---------------------------------------------------------------------------
extern "C" void kernel_launch(void* const* d_in, const int* in_sizes, int n_in,
                              void* d_out, int out_size, void* d_ws, size_t ws_size,
                              hipStream_t stream) {
    const int*   x_ids = (const int*)d_in[0];
    const int*   ei    = (const int*)d_in[1];
    const float* eattr = (const float*)d_in[2];
    const float* emb   = (const float*)d_in[3];
    const float* W1    = (const float*)d_in[4];
    const float* b1    = (const float*)d_in[5];
    const float* Wu1   = (const float*)d_in[6];
    const float* bu1   = (const float*)d_in[7];
    const float* W2    = (const float*)d_in[8];
    const float* b2    = (const float*)d_in[9];
    const float* Wu2   = (const float*)d_in[10];
    const float* bu2   = (const float*)d_in[11];

    const int N = in_sizes[0];
    const int E = in_sizes[1] / 2;
    const int* src = ei;
    const int* dst = ei + E;

    float* ws = (float*)d_ws;
    size_t stride = (size_t)N * DD;
    float* x0  = ws;
    float* x1  = ws + stride;
    float* Y   = ws + 2 * stride;
    float* agg = ws + 3 * stride;

    float* out = (float*)d_out;
    float inv_n = 1.0f / (float)N;

    hipMemsetAsync(out, 0, DD * sizeof(float), stream);

    // round 1
    init_kernel<<<1024, 256, 0, stream>>>(x_ids, emb, W1, b1, x0, Y, agg, N);
    edge_kernel<<<2048, 256, 0, stream>>>(Y, eattr, src, dst, W1, agg, E);
    node_kernel<true, false><<<1024, 256, 0, stream>>>(
        x0, agg, Wu1, bu1, W2, b2, x1, Y, agg, nullptr, N, inv_n);
    // round 2
    edge_kernel<<<2048, 256, 0, stream>>>(Y, eattr, src, dst, W2, agg, E);
    node_kernel<false, true><<<1024, 256, 0, stream>>>(
        x1, agg, Wu2, bu2, nullptr, nullptr, nullptr, nullptr, nullptr, out, N, inv_n);
}

// Round 3
// 609.142 us; speedup vs baseline: 1.5445x; 1.5445x over previous
//
#include <hip/hip_runtime.h>

#define DD    64
#define WCOLS 68   // D + EF

__device__ __forceinline__ float lane_bcast(float v, int k) {
    return __int_as_float(__builtin_amdgcn_readlane(__float_as_int(v), k));
}

// ---------------------------------------------------------------------------
// CSR build: histogram of dst
// ---------------------------------------------------------------------------
__global__ __launch_bounds__(256) void hist_kernel(
    const int* __restrict__ dst, int* __restrict__ deg, int E)
{
    int i = blockIdx.x * 256 + threadIdx.x;
    int stride = gridDim.x * 256;
    for (; i < E; i += stride) atomicAdd(&deg[dst[i]], 1);
}

// scan phase 1: exclusive scan within 1024-element chunks (256 thr x 4 items)
__global__ __launch_bounds__(256) void scan1_kernel(
    const int* __restrict__ deg, int* __restrict__ rowp, int* __restrict__ bsum, int N)
{
    __shared__ int lds[256];
    int base = blockIdx.x * 1024;
    int t = threadIdx.x;
    int idx0 = base + t * 4;
    int v[4];
    #pragma unroll
    for (int j = 0; j < 4; ++j) v[j] = (idx0 + j < N) ? deg[idx0 + j] : 0;
    lds[t] = v[0] + v[1] + v[2] + v[3];
    __syncthreads();
    for (int off = 1; off < 256; off <<= 1) {
        int x = (t >= off) ? lds[t - off] : 0;
        __syncthreads();
        lds[t] += x;
        __syncthreads();
    }
    int run = (t > 0) ? lds[t - 1] : 0;
    if (t == 255) bsum[blockIdx.x] = lds[255];
    #pragma unroll
    for (int j = 0; j < 4; ++j) {
        if (idx0 + j < N) rowp[idx0 + j] = run;
        run += v[j];
    }
}

// scan phase 2: exclusive scan of chunk totals (nchunks <= 256)
__global__ __launch_bounds__(256) void scan2_kernel(int* __restrict__ bsum, int nchunks)
{
    __shared__ int lds[256];
    int t = threadIdx.x;
    int v = (t < nchunks) ? bsum[t] : 0;
    lds[t] = v;
    __syncthreads();
    for (int off = 1; off < 256; off <<= 1) {
        int x = (t >= off) ? lds[t - off] : 0;
        __syncthreads();
        lds[t] += x;
        __syncthreads();
    }
    if (t < nchunks) bsum[t] = (t > 0) ? lds[t - 1] : 0;
}

// scan phase 3: add chunk offsets; init cursor; rowp[N] = E
__global__ __launch_bounds__(256) void scan3_kernel(
    int* __restrict__ rowp, const int* __restrict__ bsum, int* __restrict__ cursor,
    int N, int E)
{
    int i = blockIdx.x * 256 + threadIdx.x;
    if (i == 0) rowp[N] = E;
    if (i < N) {
        int v = rowp[i] + bsum[i >> 10];
        rowp[i] = v;
        cursor[i] = v;
    }
}

// CSR fill: permute src + edge_attr into dst-grouped order
__global__ __launch_bounds__(256) void fill_kernel(
    const int* __restrict__ src, const int* __restrict__ dst,
    const float* __restrict__ eattr, int* __restrict__ cursor,
    int* __restrict__ srcp, float4* __restrict__ eap, int E)
{
    int i = blockIdx.x * 256 + threadIdx.x;
    int stride = gridDim.x * 256;
    for (; i < E; i += stride) {
        int d = dst[i];
        int pos = atomicAdd(&cursor[d], 1);
        srcp[pos] = src[i];
        eap[pos] = *(const float4*)(eattr + (size_t)i * 4);
    }
}

// ---------------------------------------------------------------------------
// init: x = emb[x_ids];  Y = x @ W1a.T + b1
// ---------------------------------------------------------------------------
__global__ __launch_bounds__(256) void init_kernel(
    const int* __restrict__ x_ids, const float* __restrict__ emb,
    const float* __restrict__ W1, const float* __restrict__ b1,
    float* __restrict__ x0, float* __restrict__ Y, int N)
{
    __shared__ float WaT[64 * 64];              // WaT[k*64+d] = W1[d][k]
    for (int i = threadIdx.x; i < 64 * 64; i += 256) {
        int d = i & 63, k = i >> 6;
        WaT[i] = W1[d * WCOLS + k];
    }
    __syncthreads();

    int lane = threadIdx.x & 63;
    int wid  = (blockIdx.x * 256 + threadIdx.x) >> 6;
    int nw   = (gridDim.x * 256) >> 6;
    float bias = b1[lane];

    for (int base = wid * 4; base < N; base += nw * 4) {
        int nvalid = N - base; if (nvalid > 4) nvalid = 4;
        float xv[4], acc[4];
        #pragma unroll
        for (int j = 0; j < 4; ++j) {
            xv[j] = (j < nvalid) ? emb[x_ids[base + j] * DD + lane] : 0.f;
            acc[j] = bias;
        }
        #pragma unroll 8
        for (int k = 0; k < 64; ++k) {
            float w = WaT[k * 64 + lane];
            #pragma unroll
            for (int j = 0; j < 4; ++j)
                acc[j] = fmaf(w, lane_bcast(xv[j], k), acc[j]);
        }
        #pragma unroll
        for (int j = 0; j < 4; ++j) {
            if (j < nvalid) {
                size_t o = (size_t)(base + j) * DD + lane;
                x0[o] = xv[j];
                Y[o]  = acc[j];
            }
        }
    }
}

// ---------------------------------------------------------------------------
// fused round: per dst node (one wave each):
//   acc = sum_e relu(Y[src(e)] + We·ea(e))      (pull-gather, registers)
//   o   = relu((x + acc) @ Wu.T + bu)
//   FUSE_Y: x = o; Y_out = o @ Wn_a.T + bn      FINAL: out_mean += o / N
// ---------------------------------------------------------------------------
template<bool FUSE_Y, bool FINAL>
__global__ __launch_bounds__(256) void fused_kernel(
    const int* __restrict__ rowp, const int* __restrict__ srcp,
    const float4* __restrict__ eap, const float* __restrict__ Y_in,
    const float* __restrict__ Wm,
    const float* __restrict__ Wu, const float* __restrict__ bu,
    const float* __restrict__ Wn, const float* __restrict__ bn,
    float* __restrict__ x_io, float* __restrict__ Y_out,
    float* __restrict__ out_mean, int N, float inv_n)
{
    __shared__ float WuT[64 * 64];
    __shared__ float WnT[FUSE_Y ? 64 * 64 : 1];
    __shared__ float red[FINAL ? 256 : 1];
    for (int i = threadIdx.x; i < 64 * 64; i += 256) {
        int d = i & 63, k = i >> 6;
        WuT[i] = Wu[d * DD + k];
        if (FUSE_Y) WnT[i] = Wn[d * WCOLS + k];
    }
    __syncthreads();

    int lane = threadIdx.x & 63;
    // wave-uniform wave id -> rowp/srcp/eap addresses become scalar loads
    int wid  = __builtin_amdgcn_readfirstlane((blockIdx.x * 256 + (int)threadIdx.x) >> 6);
    int nw   = (gridDim.x * 256) >> 6;
    float w0 = Wm[lane * WCOLS + 64];
    float w1 = Wm[lane * WCOLS + 65];
    float w2 = Wm[lane * WCOLS + 66];
    float w3 = Wm[lane * WCOLS + 67];
    float biasu = bu[lane];
    float biasn = FUSE_Y ? bn[lane] : 0.f;
    float lsum = 0.f;

    for (int n = wid; n < N; n += nw) {
        int beg = rowp[n], end = rowp[n + 1];
        float acc = 0.f;
        int e = beg;
        // 4-edge unroll: four independent 256B Y-gathers in flight
        for (; e + 3 < end; e += 4) {
            int s0 = srcp[e], s1 = srcp[e + 1], s2 = srcp[e + 2], s3 = srcp[e + 3];
            float4 a0 = eap[e], a1 = eap[e + 1], a2 = eap[e + 2], a3 = eap[e + 3];
            float y0 = Y_in[(size_t)s0 * DD + lane];
            float y1 = Y_in[(size_t)s1 * DD + lane];
            float y2 = Y_in[(size_t)s2 * DD + lane];
            float y3 = Y_in[(size_t)s3 * DD + lane];
            float m0 = y0 + w0 * a0.x + w1 * a0.y + w2 * a0.z + w3 * a0.w;
            float m1 = y1 + w0 * a1.x + w1 * a1.y + w2 * a1.z + w3 * a1.w;
            float m2 = y2 + w0 * a2.x + w1 * a2.y + w2 * a2.z + w3 * a2.w;
            float m3 = y3 + w0 * a3.x + w1 * a3.y + w2 * a3.z + w3 * a3.w;
            acc += fmaxf(m0, 0.f) + fmaxf(m1, 0.f) + fmaxf(m2, 0.f) + fmaxf(m3, 0.f);
        }
        for (; e < end; ++e) {
            int s0 = srcp[e];
            float4 a0 = eap[e];
            float y0 = Y_in[(size_t)s0 * DD + lane];
            float m0 = y0 + w0 * a0.x + w1 * a0.y + w2 * a0.z + w3 * a0.w;
            acc += fmaxf(m0, 0.f);
        }

        size_t o = (size_t)n * DD + lane;
        float v = x_io[o] + acc;
        float au = biasu;
        #pragma unroll 8
        for (int k = 0; k < 64; ++k)
            au = fmaf(WuT[k * 64 + lane], lane_bcast(v, k), au);
        float oo = fmaxf(au, 0.f);

        if (FUSE_Y) {
            float an = biasn;
            #pragma unroll 8
            for (int k = 0; k < 64; ++k)
                an = fmaf(WnT[k * 64 + lane], lane_bcast(oo, k), an);
            x_io[o]  = oo;
            Y_out[o] = an;
        }
        if (FINAL) lsum += oo;
    }

    if (FINAL) {
        red[threadIdx.x] = lsum;
        __syncthreads();
        if (threadIdx.x < 64) {
            float s = red[threadIdx.x] + red[threadIdx.x + 64] +
                      red[threadIdx.x + 128] + red[threadIdx.x + 192];
            unsafeAtomicAdd(&out_mean[threadIdx.x], s * inv_n);
        }
    }
}

// ---------------------------------------------------------------------------
extern "C" void kernel_launch(void* const* d_in, const int* in_sizes, int n_in,
                              void* d_out, int out_size, void* d_ws, size_t ws_size,
                              hipStream_t stream) {
    const int*   x_ids = (const int*)d_in[0];
    const int*   ei    = (const int*)d_in[1];
    const float* eattr = (const float*)d_in[2];
    const float* emb   = (const float*)d_in[3];
    const float* W1    = (const float*)d_in[4];
    const float* b1    = (const float*)d_in[5];
    const float* Wu1   = (const float*)d_in[6];
    const float* bu1   = (const float*)d_in[7];
    const float* W2    = (const float*)d_in[8];
    const float* b2    = (const float*)d_in[9];
    const float* Wu2   = (const float*)d_in[10];
    const float* bu2   = (const float*)d_in[11];

    const int N = in_sizes[0];
    const int E = in_sizes[1] / 2;
    const int* src = ei;
    const int* dst = ei + E;

    float* ws = (float*)d_ws;
    size_t stride = (size_t)N * DD;
    float*  x    = ws;                       // N*64
    float*  Ya   = ws + stride;              // N*64
    float*  Yb   = ws + 2 * stride;          // N*64
    float*  eapf = ws + 3 * stride;          // E*4 (16B-aligned)
    int*    srcp = (int*)(eapf + (size_t)E * 4);   // E
    int*    rowp = srcp + E;                 // N+1
    int*    deg  = rowp + N + 1;             // N
    int*    cur  = deg + N;                  // N
    int*    bsum = cur + N;                  // nchunks (<=256)
    float4* eap  = (float4*)eapf;

    float* out = (float*)d_out;
    float inv_n = 1.0f / (float)N;
    int nchunks = (N + 1023) / 1024;

    hipMemsetAsync(deg, 0, (size_t)N * sizeof(int), stream);
    hipMemsetAsync(out, 0, DD * sizeof(float), stream);

    // CSR build
    hist_kernel <<<2048, 256, 0, stream>>>(dst, deg, E);
    scan1_kernel<<<nchunks, 256, 0, stream>>>(deg, rowp, bsum, N);
    scan2_kernel<<<1, 256, 0, stream>>>(bsum, nchunks);
    scan3_kernel<<<(N + 255) / 256, 256, 0, stream>>>(rowp, bsum, cur, N, E);
    fill_kernel <<<2048, 256, 0, stream>>>(src, dst, eattr, cur, srcp, eap, E);

    // x = emb[x_ids]; Ya = x @ W1a.T + b1
    init_kernel<<<1024, 256, 0, stream>>>(x_ids, emb, W1, b1, x, Ya, N);

    // round 1 (writes x in place, Yb for round 2)
    fused_kernel<true, false><<<2048, 256, 0, stream>>>(
        rowp, srcp, eap, Ya, W1, Wu1, bu1, W2, b2, x, Yb, nullptr, N, inv_n);
    // round 2 (final mean)
    fused_kernel<false, true><<<2048, 256, 0, stream>>>(
        rowp, srcp, eap, Yb, W2, Wu2, bu2, nullptr, nullptr, x, nullptr, out, N, inv_n);
}